// Round 7
// baseline (381.433 us; speedup 1.0000x reference)
//
#include <hip/hip_runtime.h>
#include <math.h>

#define N_NODES 100000
#define NPAD 100032         // 1563 * 64, padded row count
#define N_EDGES 1600000
#define EPS 1e-5f
#define NC 256              // edge chunks
#define CHUNK 6250          // N_EDGES / NC
#define NR 98               // ceil(100000/1024) dst ranges
#define RSZ 1024            // nodes per range
#define NRC (NR * NC)       // 25088
#define EIXL_CAP 1792       // staged edge-index capacity, 64-node blocks (l2g)
#define EIXL_CAP_G 896      // staged edge-index capacity, 32-node blocks (gemm)

typedef __bf16 bf16x8 __attribute__((ext_vector_type(8)));
typedef float f32x4 __attribute__((ext_vector_type(4)));
typedef float f32x2 __attribute__((ext_vector_type(2)));

__device__ inline unsigned short f2bf(float f) {    // RNE, finite inputs
    unsigned u = __float_as_uint(f);
    unsigned r = u + 0x7fffu + ((u >> 16) & 1u);
    return (unsigned short)(r >> 16);
}
__device__ inline float bflo(unsigned u) { return __uint_as_float(u << 16); }
__device__ inline float bfhi(unsigned u) { return __uint_as_float(u & 0xffff0000u); }
__device__ inline unsigned pack2(float lo, float hi) {
    return (unsigned)f2bf(lo) | ((unsigned)f2bf(hi) << 16);
}
__device__ inline unsigned char f2fp8(float f) {    // e4m3 via HW cvt
    return (unsigned char)(__builtin_amdgcn_cvt_pk_fp8_f32(f, f, 0, false) & 0xff);
}

// ============ fused prep: x->bf16+fp8 cast (blocks 0..12499) + dst-range
// histogram (blocks 12500..12755) ============
__global__ __launch_bounds__(256) void k_prep(const float* __restrict__ x,
                                              unsigned short* __restrict__ xb,
                                              unsigned* __restrict__ xq8,
                                              const int* __restrict__ dst,
                                              int* __restrict__ cntG) {
    __shared__ int hist[NR];
    int t = threadIdx.x;
    if (blockIdx.x < 12500) {
        int idx = blockIdx.x * 256 + t;     // < N_NODES*32 float4
        float4 v = ((const float4*)x)[idx];
        ushort4 o;
        o.x = f2bf(v.x); o.y = f2bf(v.y); o.z = f2bf(v.z); o.w = f2bf(v.w);
        ((ushort4*)xb)[idx] = o;
        int q = __builtin_amdgcn_cvt_pk_fp8_f32(v.x, v.y, 0, false);
        q = __builtin_amdgcn_cvt_pk_fp8_f32(v.z, v.w, q, true);
        xq8[idx] = (unsigned)q;
    } else {
        int c = blockIdx.x - 12500;
        for (int i = t; i < NR; i += 256) hist[i] = 0;
        __syncthreads();
        int base = c * CHUNK;
        for (int i = base + t; i < base + CHUNK; i += 256)
            atomicAdd(&hist[dst[i] >> 10], 1);
        __syncthreads();
        for (int i = t; i < NR; i += 256) cntG[i * NC + c] = hist[i];
    }
}

// ============ fused: exclusive scan of cntG (block 0) + weight prep
// (blocks 1..320) ============
__global__ __launch_bounds__(256) void k_scanA_prepw(
        int* __restrict__ cntG,
        const float* __restrict__ Wr0, const float* __restrict__ Wn0,
        const float* __restrict__ Wr1, const float* __restrict__ Wn1,
        const float* __restrict__ Wr2, const float* __restrict__ Wn2,
        unsigned short* __restrict__ WT0, unsigned short* __restrict__ WT1,
        unsigned short* __restrict__ WT2) {
    int t = threadIdx.x;
    if (blockIdx.x == 0) {
        __shared__ int ts[256];
        const int PER = NRC / 256;          // 98
        int s = 0;
        for (int i = 0; i < PER; ++i) s += cntG[t * PER + i];
        ts[t] = s;
        __syncthreads();
        #pragma unroll
        for (int off = 1; off < 256; off <<= 1) {
            int y = 0;
            if (t >= off) y = ts[t - off];
            __syncthreads();
            if (t >= off) ts[t] += y;
            __syncthreads();
        }
        int run = ts[t] - s;                // exclusive
        for (int i = 0; i < PER; ++i) {
            int v = cntG[t * PER + i];
            cntG[t * PER + i] = run;
            run += v;
        }
    } else {
        int b = blockIdx.x - 1;
        if (b < 256) {
            const float* Wr = (b < 128) ? Wr0 : Wr1;
            const float* Wn = (b < 128) ? Wn0 : Wn1;
            unsigned short* WT = (b < 128) ? WT0 : WT1;
            int idx = (b & 127) * 256 + t;
            int n = idx >> 8;
            int kc = idx & 255;
            float v = (kc < 128) ? Wr[kc * 128 + n] : Wn[(kc - 128) * 128 + n];
            WT[idx] = f2bf(v);
        } else {
            int idx = (b - 256) * 256 + t;  // < 128*128
            int n = idx >> 7;
            int k = idx & 127;
            float v = (n < 64) ? Wr2[k * 64 + n] : Wn2[k * 64 + (n - 64)];
            WT2[n * 128 + k] = f2bf(v);
        }
    }
}

// ============ bin edges by dst-range; packed (src<<10 | dstlocal) ============
__global__ __launch_bounds__(1024) void k_bin(const int* __restrict__ src,
                                              const int* __restrict__ dst,
                                              const int* __restrict__ baseG,
                                              unsigned* __restrict__ bpack) {
    __shared__ int cur[NR];
    int t = threadIdx.x, c = blockIdx.x;
    for (int i = t; i < NR; i += 1024) cur[i] = baseG[i * NC + c];
    __syncthreads();
    int base = c * CHUNK;
    for (int i = base + t; i < base + CHUNK; i += 1024) {
        int d = dst[i];
        unsigned s = (unsigned)src[i];
        int p = atomicAdd(&cur[d >> 10], 1);
        bpack[p] = (s << 10) | (unsigned)(d & 1023);
    }
}

// ============ fused per-range: histogram -> deg/invdeg/rowptr -> place =====
__global__ __launch_bounds__(1024) void k_nodeplace(
        const unsigned* __restrict__ bpack, const int* __restrict__ baseG,
        int* __restrict__ deg, float* __restrict__ invdeg,
        int* __restrict__ rowptr, int* __restrict__ eidx) {
    __shared__ int hist[RSZ];
    __shared__ int cur[RSZ];
    __shared__ int wbase[16];
    int r = blockIdx.x, t = threadIdx.x;
    hist[t] = 0;
    __syncthreads();
    int s0 = baseG[r * NC];
    int s1 = (r == NR - 1) ? N_EDGES : baseG[(r + 1) * NC];
    int nbase = r << 10;
    for (int i = s0 + t; i < s1; i += 1024)
        atomicAdd(&hist[bpack[i] & 1023u], 1);
    __syncthreads();
    int lane = t & 63, wv = t >> 6;
    int d = hist[t];
    int s = d;                              // wave-inclusive scan
    #pragma unroll
    for (int m = 1; m < 64; m <<= 1) {
        int y = __shfl_up(s, m);
        if (lane >= m) s += y;
    }
    if (lane == 63) wbase[wv] = s;
    __syncthreads();
    if (t < 16) {                           // scan the 16 wave totals
        int v = wbase[t];
        int sv = v;
        #pragma unroll
        for (int m = 1; m < 16; m <<= 1) {
            int y = __shfl_up(sv, m);
            if (t >= m) sv += y;
        }
        wbase[t] = sv - v;                  // exclusive wave base
    }
    __syncthreads();
    int p = s0 + wbase[wv] + s - d;         // exclusive prefix for counter t
    cur[t] = p;
    int n = nbase + t;
    if (n < N_NODES) {
        rowptr[n] = p;
        deg[n] = d;
        invdeg[n] = 1.0f / fmaxf((float)d, 1.0f);
    }
    __syncthreads();
    for (int i = s0 + t; i < s1; i += 1024) {
        unsigned bp = bpack[i];
        int pp = atomicAdd(&cur[bp & 1023u], 1);
        eidx[pp] = (int)(bp >> 10);
    }
}

// ------ MFMA dual-GEMM + bias + LayerNorm + ReLU (K=256 -> 128), 32 rows ---
// 256 threads / 4 waves, 32 rows per block. No bt tile: B-fragments load
// straight from global WT (64 KB, L2-resident) into registers each K-step,
// so the K-loop has ZERO barriers. No hl tile: self A-fragments in regs.
// LDS = al 8.7K + p 0.5K + eixl 3.5K = 12.8 KB -> 8 blocks/CU = 32 waves
// (wave-capacity max), grid depth 3126/256 = 12 blocks/CU -> smooth drain.
__global__ __launch_bounds__(256, 8) void k_gemm_ln(
        const unsigned short* __restrict__ hb,
        const uint4* __restrict__ hq4,
        const int* __restrict__ eidx, const int* __restrict__ rowptr,
        const int* __restrict__ deg, const float* __restrict__ invdeg,
        const unsigned short* __restrict__ WT,
        const float* __restrict__ b, const float* __restrict__ g,
        const float* __restrict__ be, unsigned short* __restrict__ outb,
        unsigned char* __restrict__ outq8) {
    __shared__ unsigned short al[32][136];
    __shared__ float p1[2][32], p2[2][32];
    __shared__ int eixl[EIXL_CAP_G];

    const int tid = threadIdx.x;
    const int lane = tid & 63;
    const int w = tid >> 6;         // 0..3
    const int quad = lane >> 4;
    const int l15 = lane & 15;
    const int rt = w >> 1;          // 0..1 (row tile)
    const int ch = w & 1;           // 0..1 (col half)
    const int row0 = blockIdx.x * 32;

    // self A-fragments (K 0..127) straight to registers, issued first so the
    // loads ride under the gather latency
    bf16x8 selfA[4];
    {
        const unsigned short* base = hb + (size_t)(row0 + rt * 16 + l15) * 128 + quad * 8;
        #pragma unroll
        for (int kt = 0; kt < 4; ++kt)
            selfA[kt] = *(const bf16x8*)(base + kt * 32);
    }

    // stage this block's contiguous edge-index segment
    int e0 = (row0 < N_NODES) ? rowptr[row0] : N_EDGES;
    int e1 = (row0 + 32 < N_NODES) ? rowptr[row0 + 32] : N_EDGES;
    int nE = e1 - e0;
    int staged = nE < EIXL_CAP_G ? nE : EIXL_CAP_G;
    for (int i = tid; i < staged; i += 256) eixl[i] = eidx[e0 + i];
    __syncthreads();

    // fused gather: node = row0 + tid/8, lane l = tid&7 owns 16B of the row
    {
        int r = tid >> 3;               // 0..31
        int l = tid & 7;
        int node = row0 + r;
        uint4 o0 = {0, 0, 0, 0}, o1 = {0, 0, 0, 0};
        if (node < N_NODES) {
            int start = rowptr[node];
            int cnt = deg[node];
            int rel = start - e0;
            f32x2 a[8];
            #pragma unroll
            for (int i = 0; i < 8; ++i) a[i] = (f32x2)0.0f;
            auto accum = [&](uint4 u) {
                a[0] += __builtin_amdgcn_cvt_pk_f32_fp8((int)u.x, false);
                a[1] += __builtin_amdgcn_cvt_pk_f32_fp8((int)u.x, true);
                a[2] += __builtin_amdgcn_cvt_pk_f32_fp8((int)u.y, false);
                a[3] += __builtin_amdgcn_cvt_pk_f32_fp8((int)u.y, true);
                a[4] += __builtin_amdgcn_cvt_pk_f32_fp8((int)u.z, false);
                a[5] += __builtin_amdgcn_cvt_pk_f32_fp8((int)u.z, true);
                a[6] += __builtin_amdgcn_cvt_pk_f32_fp8((int)u.w, false);
                a[7] += __builtin_amdgcn_cvt_pk_f32_fp8((int)u.w, true);
            };
            if (rel + cnt <= staged) {      // whole node staged (normal case)
                int j = 0;
                for (; j + 4 <= cnt; j += 4) {
                    int i0 = eixl[rel + j + 0], i1 = eixl[rel + j + 1];
                    int i2 = eixl[rel + j + 2], i3 = eixl[rel + j + 3];
                    uint4 u0 = hq4[(unsigned)(i0 * 8 + l)];
                    uint4 u1 = hq4[(unsigned)(i1 * 8 + l)];
                    uint4 u2 = hq4[(unsigned)(i2 * 8 + l)];
                    uint4 u3 = hq4[(unsigned)(i3 * 8 + l)];
                    accum(u0); accum(u1); accum(u2); accum(u3);
                }
                for (; j < cnt; ++j) {
                    uint4 u = hq4[(unsigned)(eixl[rel + j] * 8 + l)];
                    accum(u);
                }
            } else {                        // overflow fallback (astronomically rare)
                int j = 0;
                for (; j + 4 <= cnt; j += 4) {
                    int s0 = eidx[start + j];
                    int s1 = eidx[start + j + 1];
                    int s2 = eidx[start + j + 2];
                    int s3 = eidx[start + j + 3];
                    uint4 u0 = hq4[(unsigned)(s0 * 8 + l)];
                    uint4 u1 = hq4[(unsigned)(s1 * 8 + l)];
                    uint4 u2 = hq4[(unsigned)(s2 * 8 + l)];
                    uint4 u3 = hq4[(unsigned)(s3 * 8 + l)];
                    accum(u0); accum(u1); accum(u2); accum(u3);
                }
                for (; j < cnt; ++j) {
                    uint4 u = hq4[(unsigned)(eidx[start + j] * 8 + l)];
                    accum(u);
                }
            }
            float id = invdeg[node];
            o0.x = pack2(a[0].x * id, a[0].y * id);
            o0.y = pack2(a[1].x * id, a[1].y * id);
            o0.z = pack2(a[2].x * id, a[2].y * id);
            o0.w = pack2(a[3].x * id, a[3].y * id);
            o1.x = pack2(a[4].x * id, a[4].y * id);
            o1.y = pack2(a[5].x * id, a[5].y * id);
            o1.z = pack2(a[6].x * id, a[6].y * id);
            o1.w = pack2(a[7].x * id, a[7].y * id);
        }
        *(uint4*)&al[r][l * 16] = o0;
        *(uint4*)&al[r][l * 16 + 8] = o1;
    }
    __syncthreads();                // al ready; only barrier before the K-loop

    f32x4 acc[4];
    #pragma unroll
    for (int t = 0; t < 4; ++t)
        #pragma unroll
        for (int r = 0; r < 4; ++r) acc[t][r] = 0.0f;

    // per-wave B row bases in global WT (L2-resident)
    const unsigned short* wrow[4];
    #pragma unroll
    for (int t = 0; t < 4; ++t)
        wrow[t] = WT + (size_t)(ch * 64 + t * 16 + l15) * 256 + quad * 8;

    // barrier-free K loop: 8 steps of K=32; B-frags from global each step
    #pragma unroll
    for (int kt = 0; kt < 8; ++kt) {
        bf16x8 a = (kt < 4)
            ? selfA[kt]
            : *(const bf16x8*)&al[rt * 16 + l15][(kt - 4) * 32 + quad * 8];
        #pragma unroll
        for (int t = 0; t < 4; ++t) {
            bf16x8 bb = *(const bf16x8*)(wrow[t] + kt * 32);
            acc[t] = __builtin_amdgcn_mfma_f32_16x16x32_bf16(a, bb, acc[t], 0, 0, 0);
        }
    }

    float bcol[4], gc[4], bec[4];
    #pragma unroll
    for (int t = 0; t < 4; ++t) {
        int col = ch * 64 + t * 16 + l15;
        bcol[t] = b[col]; gc[t] = g[col]; bec[t] = be[col];
    }
    float v[4][4];
    float s1[4], s2[4];
    #pragma unroll
    for (int r = 0; r < 4; ++r) { s1[r] = 0.0f; s2[r] = 0.0f; }
    #pragma unroll
    for (int t = 0; t < 4; ++t)
        #pragma unroll
        for (int r = 0; r < 4; ++r) {
            float x = acc[t][r] + bcol[t];
            v[t][r] = x;
            s1[r] += x;
            s2[r] += x * x;
        }
    #pragma unroll
    for (int m = 1; m <= 8; m <<= 1)
        #pragma unroll
        for (int r = 0; r < 4; ++r) {
            s1[r] += __shfl_xor(s1[r], m);
            s2[r] += __shfl_xor(s2[r], m);
        }
    if (l15 == 0) {
        #pragma unroll
        for (int r = 0; r < 4; ++r) {
            int rl = rt * 16 + quad * 4 + r;
            p1[ch][rl] = s1[r];
            p2[ch][rl] = s2[r];
        }
    }
    __syncthreads();
    #pragma unroll
    for (int r = 0; r < 4; ++r) {
        int rl = rt * 16 + quad * 4 + r;
        float S1 = p1[0][rl] + p1[1][rl];
        float S2 = p2[0][rl] + p2[1][rl];
        float mean = S1 * (1.0f / 128.0f);
        float var = S2 * (1.0f / 128.0f) - mean * mean;
        float rstd = rsqrtf(var + EPS);
        #pragma unroll
        for (int t = 0; t < 4; ++t) {
            int col = ch * 64 + t * 16 + l15;
            float o = fmaxf((v[t][r] - mean) * rstd * gc[t] + bec[t], 0.0f);
            outb[(size_t)(row0 + rl) * 128 + col] = f2bf(o);
            if (outq8) outq8[(size_t)(row0 + rl) * 128 + col] = f2fp8(o);
        }
    }
}

// ------ layer 2 GEMM: z(+b2) -> bf16, y -> fp8 shadow, 64 rows -------------
__global__ __launch_bounds__(512) void k_gemm2(
        const unsigned short* __restrict__ hb, const unsigned short* __restrict__ WT,
        const float* __restrict__ b2, unsigned short* __restrict__ zb16,
        unsigned char* __restrict__ yq8) {
    __shared__ unsigned short hl[64][136];
    __shared__ unsigned short bt[128][136];

    const int tid = threadIdx.x;
    const int lane = tid & 63;
    const int w = tid >> 6;
    const int quad = lane >> 4;
    const int l15 = lane & 15;
    const int rt = w >> 1;
    const int ch = w & 1;
    const int row0 = blockIdx.x * 64;

    #pragma unroll
    for (int t = 0; t < 2; ++t) {
        int idx = tid + t * 512;
        int r = idx >> 4;
        int c8 = idx & 15;
        *(float4*)&hl[r][c8 * 8] = ((const float4*)hb)[(size_t)(row0 + r) * 16 + c8];
    }
    #pragma unroll
    for (int t = 0; t < 4; ++t) {
        int idx = tid + t * 512;
        int n = idx >> 4;
        int c8 = idx & 15;
        *(float4*)&bt[n][c8 * 8] = ((const float4*)WT)[n * 16 + c8];
    }
    __syncthreads();

    f32x4 acc[4];
    #pragma unroll
    for (int t = 0; t < 4; ++t)
        #pragma unroll
        for (int r = 0; r < 4; ++r) acc[t][r] = 0.0f;

    #pragma unroll
    for (int ks = 0; ks < 4; ++ks) {
        bf16x8 a = *(const bf16x8*)&hl[rt * 16 + l15][ks * 32 + quad * 8];
        #pragma unroll
        for (int t = 0; t < 4; ++t) {
            bf16x8 bb = *(const bf16x8*)&bt[ch * 64 + t * 16 + l15][ks * 32 + quad * 8];
            acc[t] = __builtin_amdgcn_mfma_f32_16x16x32_bf16(a, bb, acc[t], 0, 0, 0);
        }
    }

    if (ch == 0) {      // z half: cols 0..63, + bias, bf16
        #pragma unroll
        for (int t = 0; t < 4; ++t) {
            int col = t * 16 + l15;
            float bc = b2[col];
            #pragma unroll
            for (int r = 0; r < 4; ++r) {
                int rl = rt * 16 + quad * 4 + r;
                zb16[(size_t)(row0 + rl) * 64 + col] = f2bf(acc[t][r] + bc);
            }
        }
    } else {            // y half: cols 0..63 of y, fp8
        #pragma unroll
        for (int t = 0; t < 4; ++t) {
            int col = t * 16 + l15;
            #pragma unroll
            for (int r = 0; r < 4; ++r) {
                int rl = rt * 16 + quad * 4 + r;
                yq8[(size_t)(row0 + rl) * 64 + col] = f2fp8(acc[t][r]);
            }
        }
    }
}

// ------- final: gather-mean y (fp8, 64-dim) + z + log_softmax, fp32 out ----
__global__ __launch_bounds__(256) void k_l2g(const uint4* __restrict__ yq4,
                                             const unsigned short* __restrict__ zb16,
                                             const int* __restrict__ eidx,
                                             const int* __restrict__ rowptr,
                                             const int* __restrict__ deg,
                                             const float* __restrict__ invdeg,
                                             float* __restrict__ out) {
    __shared__ int eixl[EIXL_CAP];
    int node0 = blockIdx.x * 64;
    int e0 = rowptr[node0];
    int e1 = (node0 + 64 < N_NODES) ? rowptr[node0 + 64] : N_EDGES;
    int nE = e1 - e0;
    int staged = nE < EIXL_CAP ? nE : EIXL_CAP;
    for (int i = threadIdx.x; i < staged; i += 256) eixl[i] = eidx[e0 + i];
    __syncthreads();

    int node = node0 + (threadIdx.x >> 2);
    if (node >= N_NODES) return;   // after the only barrier — safe
    int l = threadIdx.x & 3;       // 16B chunk of the 64B fp8 y row
    int start = rowptr[node];
    int cnt = deg[node];
    int rel = start - e0;
    f32x2 a[8];
    #pragma unroll
    for (int i = 0; i < 8; ++i) a[i] = (f32x2)0.0f;

    auto accum = [&](uint4 u) {
        a[0] += __builtin_amdgcn_cvt_pk_f32_fp8((int)u.x, false);
        a[1] += __builtin_amdgcn_cvt_pk_f32_fp8((int)u.x, true);
        a[2] += __builtin_amdgcn_cvt_pk_f32_fp8((int)u.y, false);
        a[3] += __builtin_amdgcn_cvt_pk_f32_fp8((int)u.y, true);
        a[4] += __builtin_amdgcn_cvt_pk_f32_fp8((int)u.z, false);
        a[5] += __builtin_amdgcn_cvt_pk_f32_fp8((int)u.z, true);
        a[6] += __builtin_amdgcn_cvt_pk_f32_fp8((int)u.w, false);
        a[7] += __builtin_amdgcn_cvt_pk_f32_fp8((int)u.w, true);
    };

    if (rel + cnt <= staged) {
        int nb = cnt >> 3;
        for (int bq = 0; bq < nb; ++bq) {
            int jb = rel + bq * 8;
            int i0 = eixl[jb + 0], i1 = eixl[jb + 1];
            int i2 = eixl[jb + 2], i3 = eixl[jb + 3];
            int i4 = eixl[jb + 4], i5 = eixl[jb + 5];
            int i6 = eixl[jb + 6], i7 = eixl[jb + 7];
            uint4 u0 = yq4[(unsigned)(i0 * 4 + l)];
            uint4 u1 = yq4[(unsigned)(i1 * 4 + l)];
            uint4 u2 = yq4[(unsigned)(i2 * 4 + l)];
            uint4 u3 = yq4[(unsigned)(i3 * 4 + l)];
            uint4 u4 = yq4[(unsigned)(i4 * 4 + l)];
            uint4 u5 = yq4[(unsigned)(i5 * 4 + l)];
            uint4 u6 = yq4[(unsigned)(i6 * 4 + l)];
            uint4 u7 = yq4[(unsigned)(i7 * 4 + l)];
            accum(u0); accum(u1); accum(u2); accum(u3);
            accum(u4); accum(u5); accum(u6); accum(u7);
        }
        int j = nb << 3;
        int rem = cnt - j;
        #pragma unroll
        for (int k = 0; k < 8; ++k) {
            if (k < rem) {
                uint4 u = yq4[(unsigned)(eixl[rel + j + k] * 4 + l)];
                accum(u);
            }
        }
    } else {                        // overflow fallback (astronomically rare)
        int j = 0;
        for (; j + 4 <= cnt; j += 4) {
            int s0 = eidx[start + j];
            int s1 = eidx[start + j + 1];
            int s2 = eidx[start + j + 2];
            int s3 = eidx[start + j + 3];
            uint4 u0 = yq4[(unsigned)(s0 * 4 + l)];
            uint4 u1 = yq4[(unsigned)(s1 * 4 + l)];
            uint4 u2 = yq4[(unsigned)(s2 * 4 + l)];
            uint4 u3 = yq4[(unsigned)(s3 * 4 + l)];
            accum(u0); accum(u1); accum(u2); accum(u3);
        }
        for (; j < cnt; ++j) {
            uint4 u = yq4[(unsigned)(eidx[start + j] * 4 + l)];
            accum(u);
        }
    }

    // v = z + mean(y) for cols 16l..16l+15
    float id = invdeg[node];
    uint4 z0 = ((const uint4*)zb16)[(size_t)node * 8 + l * 2];
    uint4 z1 = ((const uint4*)zb16)[(size_t)node * 8 + l * 2 + 1];
    float v[16];
    v[0]  = bflo(z0.x) + a[0].x * id; v[1]  = bfhi(z0.x) + a[0].y * id;
    v[2]  = bflo(z0.y) + a[1].x * id; v[3]  = bfhi(z0.y) + a[1].y * id;
    v[4]  = bflo(z0.z) + a[2].x * id; v[5]  = bfhi(z0.z) + a[2].y * id;
    v[6]  = bflo(z0.w) + a[3].x * id; v[7]  = bfhi(z0.w) + a[3].y * id;
    v[8]  = bflo(z1.x) + a[4].x * id; v[9]  = bfhi(z1.x) + a[4].y * id;
    v[10] = bflo(z1.y) + a[5].x * id; v[11] = bfhi(z1.y) + a[5].y * id;
    v[12] = bflo(z1.z) + a[6].x * id; v[13] = bfhi(z1.z) + a[6].y * id;
    v[14] = bflo(z1.w) + a[7].x * id; v[15] = bfhi(z1.w) + a[7].y * id;

    float m = v[0];
    #pragma unroll
    for (int i = 1; i < 16; ++i) m = fmaxf(m, v[i]);
    m = fmaxf(m, __shfl_xor(m, 1));
    m = fmaxf(m, __shfl_xor(m, 2));
    float s = 0.0f;
    #pragma unroll
    for (int i = 0; i < 16; ++i) s += __expf(v[i] - m);
    s += __shfl_xor(s, 1);
    s += __shfl_xor(s, 2);
    float L = m + logf(s);
    #pragma unroll
    for (int k = 0; k < 4; ++k) {
        float4 o;
        o.x = v[4 * k] - L; o.y = v[4 * k + 1] - L;
        o.z = v[4 * k + 2] - L; o.w = v[4 * k + 3] - L;
        ((float4*)out)[(size_t)node * 16 + l * 4 + k] = o;
    }
}

extern "C" void kernel_launch(void* const* d_in, const int* in_sizes, int n_in,
                              void* d_out, int out_size, void* d_ws, size_t ws_size,
                              hipStream_t stream) {
    const float* x   = (const float*)d_in[0];
    const int* esrc  = (const int*)d_in[1];
    const int* edst  = (const int*)d_in[2];
    const float* Wr0 = (const float*)d_in[3];
    const float* Wn0 = (const float*)d_in[4];
    const float* b0  = (const float*)d_in[5];
    const float* g0  = (const float*)d_in[6];
    const float* be0 = (const float*)d_in[7];
    const float* Wr1 = (const float*)d_in[8];
    const float* Wn1 = (const float*)d_in[9];
    const float* b1  = (const float*)d_in[10];
    const float* g1  = (const float*)d_in[11];
    const float* be1 = (const float*)d_in[12];
    const float* Wr2 = (const float*)d_in[13];
    const float* Wn2 = (const float*)d_in[14];
    const float* b2  = (const float*)d_in[15];
    float* out = (float*)d_out;

    char* p = (char*)d_ws;
    auto alloc = [&](size_t bytes) {
        void* r = (void*)p;
        p += (bytes + 255) & ~(size_t)255;
        return r;
    };
    int*   deg    = (int*)  alloc(N_NODES * 4);
    float* invdeg = (float*)alloc(N_NODES * 4);
    int*   rowptr = (int*)  alloc(N_NODES * 4);
    int*   cntG   = (int*)  alloc(NRC * 4);
    unsigned* bpack = (unsigned*)alloc((size_t)N_EDGES * 4);
    int*   eidx   = (int*)  alloc((size_t)N_EDGES * 4);
    unsigned short* xb   = (unsigned short*)alloc((size_t)NPAD * 128 * 2); // also h2
    unsigned short* h1   = (unsigned short*)alloc((size_t)NPAD * 128 * 2);
    unsigned*       xq8  = (unsigned*)      alloc((size_t)N_NODES * 128);
    unsigned char*  h1q8 = (unsigned char*) alloc((size_t)NPAD * 128);
    unsigned short* zb16 = (unsigned short*)alloc((size_t)NPAD * 64 * 2);
    unsigned char*  yq8  = (unsigned char*) alloc((size_t)NPAD * 64);
    unsigned short* WT0  = (unsigned short*)alloc(128 * 256 * 2);
    unsigned short* WT1  = (unsigned short*)alloc(128 * 256 * 2);
    unsigned short* WT2  = (unsigned short*)alloc(128 * 128 * 2);

    // prep (cast bf16+fp8 + dst-range count); scan + weight transpose
    k_prep<<<12500 + NC, 256, 0, stream>>>(x, xb, xq8, edst, cntG);
    k_scanA_prepw<<<321, 256, 0, stream>>>(cntG, Wr0, Wn0, Wr1, Wn1, Wr2, Wn2,
                                           WT0, WT1, WT2);
    k_bin<<<NC, 1024, 0, stream>>>(esrc, edst, cntG, bpack);
    k_nodeplace<<<NR, 1024, 0, stream>>>(bpack, cntG, deg, invdeg, rowptr, eidx);

    // layer 0 (gather fused into the GEMM; 32-row blocks)
    k_gemm_ln<<<NPAD / 32, 256, 0, stream>>>(xb, (const uint4*)xq8, eidx, rowptr,
                                             deg, invdeg, WT0, b0, g0, be0, h1, h1q8);

    // layer 1 (h2 goes back into xb's buffer; no fp8 copy needed)
    k_gemm_ln<<<NPAD / 32, 256, 0, stream>>>(h1, (const uint4*)h1q8, eidx, rowptr,
                                             deg, invdeg, WT1, b1, g1, be1, xb,
                                             (unsigned char*)nullptr);

    // layer 2: z (bf16) + y (fp8), then gather y + log_softmax
    k_gemm2<<<NPAD / 64, 512, 0, stream>>>(xb, WT2, b2, zb16, yq8);
    k_l2g<<<(N_NODES + 63) / 64, 256, 0, stream>>>((const uint4*)yq8, zb16, eidx, rowptr, deg, invdeg, out);
}

// Round 8
// 340.762 us; speedup vs baseline: 1.1194x; 1.1194x over previous
//
#include <hip/hip_runtime.h>
#include <math.h>

#define N_NODES 100000
#define NPAD 100032         // 1563 * 64, padded row count for 64-row GEMM tiles
#define N_EDGES 1600000
#define EPS 1e-5f
#define NC 256              // edge chunks
#define CHUNK 6250          // N_EDGES / NC
#define NR 98               // ceil(100000/1024) dst ranges
#define RSZ 1024            // nodes per range
#define NRC (NR * NC)       // 25088
#define EIXL_CAP 1792       // staged edge-index capacity (mean 1024 + 24 sigma)

typedef __bf16 bf16x8 __attribute__((ext_vector_type(8)));
typedef float f32x4 __attribute__((ext_vector_type(4)));
typedef float f32x2 __attribute__((ext_vector_type(2)));

__device__ inline unsigned short f2bf(float f) {    // RNE, finite inputs
    unsigned u = __float_as_uint(f);
    unsigned r = u + 0x7fffu + ((u >> 16) & 1u);
    return (unsigned short)(r >> 16);
}
__device__ inline float bflo(unsigned u) { return __uint_as_float(u << 16); }
__device__ inline float bfhi(unsigned u) { return __uint_as_float(u & 0xffff0000u); }
__device__ inline unsigned pack2(float lo, float hi) {
    return (unsigned)f2bf(lo) | ((unsigned)f2bf(hi) << 16);
}
__device__ inline unsigned char f2fp8(float f) {    // e4m3 via HW cvt
    return (unsigned char)(__builtin_amdgcn_cvt_pk_fp8_f32(f, f, 0, false) & 0xff);
}

// ============ fused prep: x->bf16+fp8 cast (blocks 0..12499) + dst-range
// histogram (blocks 12500..12755) ============
__global__ __launch_bounds__(256) void k_prep(const float* __restrict__ x,
                                              unsigned short* __restrict__ xb,
                                              unsigned* __restrict__ xq8,
                                              const int* __restrict__ dst,
                                              int* __restrict__ cntG) {
    __shared__ int hist[NR];
    int t = threadIdx.x;
    if (blockIdx.x < 12500) {
        int idx = blockIdx.x * 256 + t;     // < N_NODES*32 float4
        float4 v = ((const float4*)x)[idx];
        ushort4 o;
        o.x = f2bf(v.x); o.y = f2bf(v.y); o.z = f2bf(v.z); o.w = f2bf(v.w);
        ((ushort4*)xb)[idx] = o;
        int q = __builtin_amdgcn_cvt_pk_fp8_f32(v.x, v.y, 0, false);
        q = __builtin_amdgcn_cvt_pk_fp8_f32(v.z, v.w, q, true);
        xq8[idx] = (unsigned)q;
    } else {
        int c = blockIdx.x - 12500;
        for (int i = t; i < NR; i += 256) hist[i] = 0;
        __syncthreads();
        int base = c * CHUNK;
        for (int i = base + t; i < base + CHUNK; i += 256)
            atomicAdd(&hist[dst[i] >> 10], 1);
        __syncthreads();
        for (int i = t; i < NR; i += 256) cntG[i * NC + c] = hist[i];
    }
}

// ============ fused: exclusive scan of cntG (block 0) + weight prep
// (blocks 1..320) ============
__global__ __launch_bounds__(256) void k_scanA_prepw(
        int* __restrict__ cntG,
        const float* __restrict__ Wr0, const float* __restrict__ Wn0,
        const float* __restrict__ Wr1, const float* __restrict__ Wn1,
        const float* __restrict__ Wr2, const float* __restrict__ Wn2,
        unsigned short* __restrict__ WT0, unsigned short* __restrict__ WT1,
        unsigned short* __restrict__ WT2) {
    int t = threadIdx.x;
    if (blockIdx.x == 0) {
        __shared__ int ts[256];
        const int PER = NRC / 256;          // 98
        int s = 0;
        for (int i = 0; i < PER; ++i) s += cntG[t * PER + i];
        ts[t] = s;
        __syncthreads();
        #pragma unroll
        for (int off = 1; off < 256; off <<= 1) {
            int y = 0;
            if (t >= off) y = ts[t - off];
            __syncthreads();
            if (t >= off) ts[t] += y;
            __syncthreads();
        }
        int run = ts[t] - s;                // exclusive
        for (int i = 0; i < PER; ++i) {
            int v = cntG[t * PER + i];
            cntG[t * PER + i] = run;
            run += v;
        }
    } else {
        int b = blockIdx.x - 1;
        if (b < 256) {
            const float* Wr = (b < 128) ? Wr0 : Wr1;
            const float* Wn = (b < 128) ? Wn0 : Wn1;
            unsigned short* WT = (b < 128) ? WT0 : WT1;
            int idx = (b & 127) * 256 + t;
            int n = idx >> 8;
            int kc = idx & 255;
            float v = (kc < 128) ? Wr[kc * 128 + n] : Wn[(kc - 128) * 128 + n];
            WT[idx] = f2bf(v);
        } else {
            int idx = (b - 256) * 256 + t;  // < 128*128
            int n = idx >> 7;
            int k = idx & 127;
            float v = (n < 64) ? Wr2[k * 64 + n] : Wn2[k * 64 + (n - 64)];
            WT2[n * 128 + k] = f2bf(v);
        }
    }
}

// ============ bin edges by dst-range; packed (src<<10 | dstlocal) ============
__global__ __launch_bounds__(1024) void k_bin(const int* __restrict__ src,
                                              const int* __restrict__ dst,
                                              const int* __restrict__ baseG,
                                              unsigned* __restrict__ bpack) {
    __shared__ int cur[NR];
    int t = threadIdx.x, c = blockIdx.x;
    for (int i = t; i < NR; i += 1024) cur[i] = baseG[i * NC + c];
    __syncthreads();
    int base = c * CHUNK;
    for (int i = base + t; i < base + CHUNK; i += 1024) {
        int d = dst[i];
        unsigned s = (unsigned)src[i];
        int p = atomicAdd(&cur[d >> 10], 1);
        bpack[p] = (s << 10) | (unsigned)(d & 1023);
    }
}

// ============ fused per-range: histogram -> deg/invdeg/rowptr -> place =====
__global__ __launch_bounds__(1024) void k_nodeplace(
        const unsigned* __restrict__ bpack, const int* __restrict__ baseG,
        int* __restrict__ deg, float* __restrict__ invdeg,
        int* __restrict__ rowptr, int* __restrict__ eidx) {
    __shared__ int hist[RSZ];
    __shared__ int cur[RSZ];
    __shared__ int wbase[16];
    int r = blockIdx.x, t = threadIdx.x;
    hist[t] = 0;
    __syncthreads();
    int s0 = baseG[r * NC];
    int s1 = (r == NR - 1) ? N_EDGES : baseG[(r + 1) * NC];
    int nbase = r << 10;
    for (int i = s0 + t; i < s1; i += 1024)
        atomicAdd(&hist[bpack[i] & 1023u], 1);
    __syncthreads();
    int lane = t & 63, wv = t >> 6;
    int d = hist[t];
    int s = d;                              // wave-inclusive scan
    #pragma unroll
    for (int m = 1; m < 64; m <<= 1) {
        int y = __shfl_up(s, m);
        if (lane >= m) s += y;
    }
    if (lane == 63) wbase[wv] = s;
    __syncthreads();
    if (t < 16) {                           // scan the 16 wave totals
        int v = wbase[t];
        int sv = v;
        #pragma unroll
        for (int m = 1; m < 16; m <<= 1) {
            int y = __shfl_up(sv, m);
            if (t >= m) sv += y;
        }
        wbase[t] = sv - v;                  // exclusive wave base
    }
    __syncthreads();
    int p = s0 + wbase[wv] + s - d;         // exclusive prefix for counter t
    cur[t] = p;
    int n = nbase + t;
    if (n < N_NODES) {
        rowptr[n] = p;
        deg[n] = d;
        invdeg[n] = 1.0f / fmaxf((float)d, 1.0f);
    }
    __syncthreads();
    for (int i = s0 + t; i < s1; i += 1024) {
        unsigned bp = bpack[i];
        int pp = atomicAdd(&cur[bp & 1023u], 1);
        eidx[pp] = (int)(bp >> 10);
    }
}

// ------ MFMA dual-GEMM + bias + LayerNorm + ReLU (K=256 -> 128), 64 rows ---
// r6 structure (proven 54.7us): fused gather, selfA in regs, bt K=32 LDS
// staging, 35.8KB LDS -> 4 blocks/CU. NEW: optional fused layer-2 GEMM
// (WT2 != null): the epilogue writes h2 into the dead al tile instead of
// global, then 16 MFMAs vs WT2 (32KB, L2-hot) produce z (bf16+bias) and
// y (fp8) directly — kills the h2 global write + k_gemm2's re-read+launch.
__global__ __launch_bounds__(512, 6) void k_gemm_ln(
        const unsigned short* __restrict__ hb,
        const uint4* __restrict__ hq4,
        const int* __restrict__ eidx, const int* __restrict__ rowptr,
        const int* __restrict__ deg, const float* __restrict__ invdeg,
        const unsigned short* __restrict__ WT,
        const float* __restrict__ b, const float* __restrict__ g,
        const float* __restrict__ be, unsigned short* __restrict__ outb,
        unsigned char* __restrict__ outq8,
        const unsigned short* __restrict__ WT2,
        const float* __restrict__ b2,
        unsigned short* __restrict__ zb16,
        unsigned char* __restrict__ yq8) {
    __shared__ unsigned short al[64][136];
    __shared__ unsigned short bt[128][40];
    __shared__ float p1[2][64], p2[2][64];
    __shared__ int eixl[EIXL_CAP];

    const int tid = threadIdx.x;
    const int lane = tid & 63;
    const int w = tid >> 6;
    const int quad = lane >> 4;
    const int l15 = lane & 15;
    const int rt = w >> 1;
    const int ch = w & 1;
    const int row0 = blockIdx.x * 64;

    // self A-fragments (K 0..127) straight to registers; issued first so the
    // loads ride under the gather latency
    bf16x8 selfA[4];
    {
        const unsigned short* base = hb + (size_t)(row0 + rt * 16 + l15) * 128 + quad * 8;
        #pragma unroll
        for (int kt = 0; kt < 4; ++kt)
            selfA[kt] = *(const bf16x8*)(base + kt * 32);
    }

    // stage this block's contiguous edge-index segment
    int e0 = rowptr[row0];
    int e1 = (row0 + 64 < N_NODES) ? rowptr[row0 + 64] : N_EDGES;
    int nE = e1 - e0;
    int staged = nE < EIXL_CAP ? nE : EIXL_CAP;
    for (int i = tid; i < staged; i += 512) eixl[i] = eidx[e0 + i];
    __syncthreads();

    // fused gather: node = row0 + tid/8, lane l = tid&7 owns 16B of the row
    {
        int r = tid >> 3;               // 0..63
        int l = tid & 7;
        int node = row0 + r;
        uint4 o0 = {0, 0, 0, 0}, o1 = {0, 0, 0, 0};
        if (node < N_NODES) {
            int start = rowptr[node];
            int cnt = deg[node];
            int rel = start - e0;
            f32x2 a[8];
            #pragma unroll
            for (int i = 0; i < 8; ++i) a[i] = (f32x2)0.0f;
            auto accum = [&](uint4 u) {
                a[0] += __builtin_amdgcn_cvt_pk_f32_fp8((int)u.x, false);
                a[1] += __builtin_amdgcn_cvt_pk_f32_fp8((int)u.x, true);
                a[2] += __builtin_amdgcn_cvt_pk_f32_fp8((int)u.y, false);
                a[3] += __builtin_amdgcn_cvt_pk_f32_fp8((int)u.y, true);
                a[4] += __builtin_amdgcn_cvt_pk_f32_fp8((int)u.z, false);
                a[5] += __builtin_amdgcn_cvt_pk_f32_fp8((int)u.z, true);
                a[6] += __builtin_amdgcn_cvt_pk_f32_fp8((int)u.w, false);
                a[7] += __builtin_amdgcn_cvt_pk_f32_fp8((int)u.w, true);
            };
            if (rel + cnt <= staged) {      // whole node staged (normal case)
                int j = 0;
                for (; j + 4 <= cnt; j += 4) {
                    int i0 = eixl[rel + j + 0], i1 = eixl[rel + j + 1];
                    int i2 = eixl[rel + j + 2], i3 = eixl[rel + j + 3];
                    uint4 u0 = hq4[(unsigned)(i0 * 8 + l)];
                    uint4 u1 = hq4[(unsigned)(i1 * 8 + l)];
                    uint4 u2 = hq4[(unsigned)(i2 * 8 + l)];
                    uint4 u3 = hq4[(unsigned)(i3 * 8 + l)];
                    accum(u0); accum(u1); accum(u2); accum(u3);
                }
                for (; j < cnt; ++j) {
                    uint4 u = hq4[(unsigned)(eixl[rel + j] * 8 + l)];
                    accum(u);
                }
            } else {                        // overflow fallback (astronomically rare)
                int j = 0;
                for (; j + 4 <= cnt; j += 4) {
                    int s0 = eidx[start + j];
                    int s1 = eidx[start + j + 1];
                    int s2 = eidx[start + j + 2];
                    int s3 = eidx[start + j + 3];
                    uint4 u0 = hq4[(unsigned)(s0 * 8 + l)];
                    uint4 u1 = hq4[(unsigned)(s1 * 8 + l)];
                    uint4 u2 = hq4[(unsigned)(s2 * 8 + l)];
                    uint4 u3 = hq4[(unsigned)(s3 * 8 + l)];
                    accum(u0); accum(u1); accum(u2); accum(u3);
                }
                for (; j < cnt; ++j) {
                    uint4 u = hq4[(unsigned)(eidx[start + j] * 8 + l)];
                    accum(u);
                }
            }
            float id = invdeg[node];
            o0.x = pack2(a[0].x * id, a[0].y * id);
            o0.y = pack2(a[1].x * id, a[1].y * id);
            o0.z = pack2(a[2].x * id, a[2].y * id);
            o0.w = pack2(a[3].x * id, a[3].y * id);
            o1.x = pack2(a[4].x * id, a[4].y * id);
            o1.y = pack2(a[5].x * id, a[5].y * id);
            o1.z = pack2(a[6].x * id, a[6].y * id);
            o1.w = pack2(a[7].x * id, a[7].y * id);
        }
        *(uint4*)&al[r][l * 16] = o0;
        *(uint4*)&al[r][l * 16 + 8] = o1;
    }

    f32x4 acc[4];
    #pragma unroll
    for (int t = 0; t < 4; ++t)
        #pragma unroll
        for (int r = 0; r < 4; ++r) acc[t][r] = 0.0f;

    // K loop: 8 steps of K=32; bt stages 128 N-rows x 32 k each step.
    // A-frag: kt<4 -> register selfA; kt>=4 -> ds_read from al.
    #pragma unroll
    for (int kt = 0; kt < 8; ++kt) {
        __syncthreads();
        {
            int n = tid >> 2;           // 0..127
            int c = tid & 3;            // 4 x float4 = 32 k-cols
            *(float4*)&bt[n][c * 8] = ((const float4*)WT)[n * 32 + kt * 4 + c];
        }
        __syncthreads();
        bf16x8 a = (kt < 4)
            ? selfA[kt]
            : *(const bf16x8*)&al[rt * 16 + l15][(kt - 4) * 32 + quad * 8];
        #pragma unroll
        for (int t = 0; t < 4; ++t) {
            bf16x8 bb = *(const bf16x8*)&bt[ch * 64 + t * 16 + l15][quad * 8];
            acc[t] = __builtin_amdgcn_mfma_f32_16x16x32_bf16(a, bb, acc[t], 0, 0, 0);
        }
    }

    float bcol[4], gc[4], bec[4];
    #pragma unroll
    for (int t = 0; t < 4; ++t) {
        int col = ch * 64 + t * 16 + l15;
        bcol[t] = b[col]; gc[t] = g[col]; bec[t] = be[col];
    }
    float v[4][4];
    float s1[4], s2[4];
    #pragma unroll
    for (int r = 0; r < 4; ++r) { s1[r] = 0.0f; s2[r] = 0.0f; }
    #pragma unroll
    for (int t = 0; t < 4; ++t)
        #pragma unroll
        for (int r = 0; r < 4; ++r) {
            float x = acc[t][r] + bcol[t];
            v[t][r] = x;
            s1[r] += x;
            s2[r] += x * x;
        }
    #pragma unroll
    for (int m = 1; m <= 8; m <<= 1)
        #pragma unroll
        for (int r = 0; r < 4; ++r) {
            s1[r] += __shfl_xor(s1[r], m);
            s2[r] += __shfl_xor(s2[r], m);
        }
    if (l15 == 0) {
        #pragma unroll
        for (int r = 0; r < 4; ++r) {
            int rl = rt * 16 + quad * 4 + r;
            p1[ch][rl] = s1[r];
            p2[ch][rl] = s2[r];
        }
    }
    __syncthreads();    // all al reads (K-loop) complete before any al rewrite
    #pragma unroll
    for (int r = 0; r < 4; ++r) {
        int rl = rt * 16 + quad * 4 + r;
        float S1 = p1[0][rl] + p1[1][rl];
        float S2 = p2[0][rl] + p2[1][rl];
        float mean = S1 * (1.0f / 128.0f);
        float var = S2 * (1.0f / 128.0f) - mean * mean;
        float rstd = rsqrtf(var + EPS);
        #pragma unroll
        for (int t = 0; t < 4; ++t) {
            int col = ch * 64 + t * 16 + l15;
            float o = fmaxf((v[t][r] - mean) * rstd * gc[t] + bec[t], 0.0f);
            if (!WT2) {
                outb[(size_t)(row0 + rl) * 128 + col] = f2bf(o);
                if (outq8) outq8[(size_t)(row0 + rl) * 128 + col] = f2fp8(o);
            } else {
                al[rl][col] = f2bf(o);      // h2 tile, feeds fused gemm2
            }
        }
    }

    if (WT2) {          // fused layer-2 GEMM: z = h2@Wr2+b2 (bf16), y = h2@Wn2 (fp8)
        __syncthreads();
        f32x4 acc2[4];
        #pragma unroll
        for (int t = 0; t < 4; ++t)
            #pragma unroll
            for (int r = 0; r < 4; ++r) acc2[t][r] = 0.0f;
        #pragma unroll
        for (int kt = 0; kt < 4; ++kt) {
            bf16x8 a = *(const bf16x8*)&al[rt * 16 + l15][kt * 32 + quad * 8];
            #pragma unroll
            for (int t = 0; t < 4; ++t) {
                bf16x8 bb = *(const bf16x8*)(WT2 +
                    (size_t)(ch * 64 + t * 16 + l15) * 128 + kt * 32 + quad * 8);
                acc2[t] = __builtin_amdgcn_mfma_f32_16x16x32_bf16(a, bb, acc2[t], 0, 0, 0);
            }
        }
        if (ch == 0) {  // z half (cols 0..63): + bias, bf16
            #pragma unroll
            for (int t = 0; t < 4; ++t) {
                int col = t * 16 + l15;
                float bc = b2[col];
                #pragma unroll
                for (int r = 0; r < 4; ++r) {
                    int rl = rt * 16 + quad * 4 + r;
                    zb16[(size_t)(row0 + rl) * 64 + col] = f2bf(acc2[t][r] + bc);
                }
            }
        } else {        // y half: fp8
            #pragma unroll
            for (int t = 0; t < 4; ++t) {
                int col = t * 16 + l15;
                #pragma unroll
                for (int r = 0; r < 4; ++r) {
                    int rl = rt * 16 + quad * 4 + r;
                    yq8[(size_t)(row0 + rl) * 64 + col] = f2fp8(acc2[t][r]);
                }
            }
        }
    }
}

// ------- final: gather-mean y (fp8, 64-dim) + z + log_softmax, fp32 out ----
__global__ __launch_bounds__(256) void k_l2g(const uint4* __restrict__ yq4,
                                             const unsigned short* __restrict__ zb16,
                                             const int* __restrict__ eidx,
                                             const int* __restrict__ rowptr,
                                             const int* __restrict__ deg,
                                             const float* __restrict__ invdeg,
                                             float* __restrict__ out) {
    __shared__ int eixl[EIXL_CAP];
    int node0 = blockIdx.x * 64;
    int e0 = rowptr[node0];
    int e1 = (node0 + 64 < N_NODES) ? rowptr[node0 + 64] : N_EDGES;
    int nE = e1 - e0;
    int staged = nE < EIXL_CAP ? nE : EIXL_CAP;
    for (int i = threadIdx.x; i < staged; i += 256) eixl[i] = eidx[e0 + i];
    __syncthreads();

    int node = node0 + (threadIdx.x >> 2);
    if (node >= N_NODES) return;   // after the only barrier — safe
    int l = threadIdx.x & 3;       // 16B chunk of the 64B fp8 y row
    int start = rowptr[node];
    int cnt = deg[node];
    int rel = start - e0;
    f32x2 a[8];
    #pragma unroll
    for (int i = 0; i < 8; ++i) a[i] = (f32x2)0.0f;

    auto accum = [&](uint4 u) {
        a[0] += __builtin_amdgcn_cvt_pk_f32_fp8((int)u.x, false);
        a[1] += __builtin_amdgcn_cvt_pk_f32_fp8((int)u.x, true);
        a[2] += __builtin_amdgcn_cvt_pk_f32_fp8((int)u.y, false);
        a[3] += __builtin_amdgcn_cvt_pk_f32_fp8((int)u.y, true);
        a[4] += __builtin_amdgcn_cvt_pk_f32_fp8((int)u.z, false);
        a[5] += __builtin_amdgcn_cvt_pk_f32_fp8((int)u.z, true);
        a[6] += __builtin_amdgcn_cvt_pk_f32_fp8((int)u.w, false);
        a[7] += __builtin_amdgcn_cvt_pk_f32_fp8((int)u.w, true);
    };

    if (rel + cnt <= staged) {
        int nb = cnt >> 3;
        for (int bq = 0; bq < nb; ++bq) {
            int jb = rel + bq * 8;
            int i0 = eixl[jb + 0], i1 = eixl[jb + 1];
            int i2 = eixl[jb + 2], i3 = eixl[jb + 3];
            int i4 = eixl[jb + 4], i5 = eixl[jb + 5];
            int i6 = eixl[jb + 6], i7 = eixl[jb + 7];
            uint4 u0 = yq4[(unsigned)(i0 * 4 + l)];
            uint4 u1 = yq4[(unsigned)(i1 * 4 + l)];
            uint4 u2 = yq4[(unsigned)(i2 * 4 + l)];
            uint4 u3 = yq4[(unsigned)(i3 * 4 + l)];
            uint4 u4 = yq4[(unsigned)(i4 * 4 + l)];
            uint4 u5 = yq4[(unsigned)(i5 * 4 + l)];
            uint4 u6 = yq4[(unsigned)(i6 * 4 + l)];
            uint4 u7 = yq4[(unsigned)(i7 * 4 + l)];
            accum(u0); accum(u1); accum(u2); accum(u3);
            accum(u4); accum(u5); accum(u6); accum(u7);
        }
        int j = nb << 3;
        int rem = cnt - j;
        #pragma unroll
        for (int k = 0; k < 8; ++k) {
            if (k < rem) {
                uint4 u = yq4[(unsigned)(eixl[rel + j + k] * 4 + l)];
                accum(u);
            }
        }
    } else {                        // overflow fallback (astronomically rare)
        int j = 0;
        for (; j + 4 <= cnt; j += 4) {
            int s0 = eidx[start + j];
            int s1 = eidx[start + j + 1];
            int s2 = eidx[start + j + 2];
            int s3 = eidx[start + j + 3];
            uint4 u0 = yq4[(unsigned)(s0 * 4 + l)];
            uint4 u1 = yq4[(unsigned)(s1 * 4 + l)];
            uint4 u2 = yq4[(unsigned)(s2 * 4 + l)];
            uint4 u3 = yq4[(unsigned)(s3 * 4 + l)];
            accum(u0); accum(u1); accum(u2); accum(u3);
        }
        for (; j < cnt; ++j) {
            uint4 u = yq4[(unsigned)(eidx[start + j] * 4 + l)];
            accum(u);
        }
    }

    // v = z + mean(y) for cols 16l..16l+15
    float id = invdeg[node];
    uint4 z0 = ((const uint4*)zb16)[(size_t)node * 8 + l * 2];
    uint4 z1 = ((const uint4*)zb16)[(size_t)node * 8 + l * 2 + 1];
    float v[16];
    v[0]  = bflo(z0.x) + a[0].x * id; v[1]  = bfhi(z0.x) + a[0].y * id;
    v[2]  = bflo(z0.y) + a[1].x * id; v[3]  = bfhi(z0.y) + a[1].y * id;
    v[4]  = bflo(z0.z) + a[2].x * id; v[5]  = bfhi(z0.z) + a[2].y * id;
    v[6]  = bflo(z0.w) + a[3].x * id; v[7]  = bfhi(z0.w) + a[3].y * id;
    v[8]  = bflo(z1.x) + a[4].x * id; v[9]  = bfhi(z1.x) + a[4].y * id;
    v[10] = bflo(z1.y) + a[5].x * id; v[11] = bfhi(z1.y) + a[5].y * id;
    v[12] = bflo(z1.z) + a[6].x * id; v[13] = bfhi(z1.z) + a[6].y * id;
    v[14] = bflo(z1.w) + a[7].x * id; v[15] = bfhi(z1.w) + a[7].y * id;

    float m = v[0];
    #pragma unroll
    for (int i = 1; i < 16; ++i) m = fmaxf(m, v[i]);
    m = fmaxf(m, __shfl_xor(m, 1));
    m = fmaxf(m, __shfl_xor(m, 2));
    float s = 0.0f;
    #pragma unroll
    for (int i = 0; i < 16; ++i) s += __expf(v[i] - m);
    s += __shfl_xor(s, 1);
    s += __shfl_xor(s, 2);
    float L = m + logf(s);
    #pragma unroll
    for (int k = 0; k < 4; ++k) {
        float4 o;
        o.x = v[4 * k] - L; o.y = v[4 * k + 1] - L;
        o.z = v[4 * k + 2] - L; o.w = v[4 * k + 3] - L;
        ((float4*)out)[(size_t)node * 16 + l * 4 + k] = o;
    }
}

extern "C" void kernel_launch(void* const* d_in, const int* in_sizes, int n_in,
                              void* d_out, int out_size, void* d_ws, size_t ws_size,
                              hipStream_t stream) {
    const float* x   = (const float*)d_in[0];
    const int* esrc  = (const int*)d_in[1];
    const int* edst  = (const int*)d_in[2];
    const float* Wr0 = (const float*)d_in[3];
    const float* Wn0 = (const float*)d_in[4];
    const float* b0  = (const float*)d_in[5];
    const float* g0  = (const float*)d_in[6];
    const float* be0 = (const float*)d_in[7];
    const float* Wr1 = (const float*)d_in[8];
    const float* Wn1 = (const float*)d_in[9];
    const float* b1  = (const float*)d_in[10];
    const float* g1  = (const float*)d_in[11];
    const float* be1 = (const float*)d_in[12];
    const float* Wr2 = (const float*)d_in[13];
    const float* Wn2 = (const float*)d_in[14];
    const float* b2  = (const float*)d_in[15];
    float* out = (float*)d_out;

    char* p = (char*)d_ws;
    auto alloc = [&](size_t bytes) {
        void* r = (void*)p;
        p += (bytes + 255) & ~(size_t)255;
        return r;
    };
    int*   deg    = (int*)  alloc(N_NODES * 4);
    float* invdeg = (float*)alloc(N_NODES * 4);
    int*   rowptr = (int*)  alloc(N_NODES * 4);
    int*   cntG   = (int*)  alloc(NRC * 4);
    unsigned* bpack = (unsigned*)alloc((size_t)N_EDGES * 4);
    int*   eidx   = (int*)  alloc((size_t)N_EDGES * 4);
    unsigned short* xb   = (unsigned short*)alloc((size_t)NPAD * 128 * 2);
    unsigned short* h1   = (unsigned short*)alloc((size_t)NPAD * 128 * 2);
    unsigned*       xq8  = (unsigned*)      alloc((size_t)N_NODES * 128);
    unsigned char*  h1q8 = (unsigned char*) alloc((size_t)NPAD * 128);
    unsigned short* zb16 = (unsigned short*)alloc((size_t)NPAD * 64 * 2);
    unsigned char*  yq8  = (unsigned char*) alloc((size_t)NPAD * 64);
    unsigned short* WT0  = (unsigned short*)alloc(128 * 256 * 2);
    unsigned short* WT1  = (unsigned short*)alloc(128 * 256 * 2);
    unsigned short* WT2  = (unsigned short*)alloc(128 * 128 * 2);

    // prep (cast bf16+fp8 + dst-range count); scan + weight transpose
    k_prep<<<12500 + NC, 256, 0, stream>>>(x, xb, xq8, edst, cntG);
    k_scanA_prepw<<<321, 256, 0, stream>>>(cntG, Wr0, Wn0, Wr1, Wn1, Wr2, Wn2,
                                           WT0, WT1, WT2);
    k_bin<<<NC, 1024, 0, stream>>>(esrc, edst, cntG, bpack);
    k_nodeplace<<<NR, 1024, 0, stream>>>(bpack, cntG, deg, invdeg, rowptr, eidx);

    // layer 0 (gather fused into the GEMM)
    k_gemm_ln<<<NPAD / 64, 512, 0, stream>>>(xb, (const uint4*)xq8, eidx, rowptr,
                                             deg, invdeg, WT0, b0, g0, be0, h1, h1q8,
                                             (const unsigned short*)nullptr,
                                             (const float*)nullptr,
                                             (unsigned short*)nullptr,
                                             (unsigned char*)nullptr);

    // layer 1 + fused layer-2 GEMM: h2 never leaves LDS; z/y written directly
    k_gemm_ln<<<NPAD / 64, 512, 0, stream>>>(h1, (const uint4*)h1q8, eidx, rowptr,
                                             deg, invdeg, WT1, b1, g1, be1,
                                             (unsigned short*)nullptr,
                                             (unsigned char*)nullptr,
                                             WT2, b2, zb16, yq8);

    // gather y + log_softmax
    k_l2g<<<(N_NODES + 63) / 64, 256, 0, stream>>>((const uint4*)yq8, zb16, eidx, rowptr, deg, invdeg, out);
}

// Round 9
// 318.031 us; speedup vs baseline: 1.1994x; 1.0715x over previous
//
#include <hip/hip_runtime.h>
#include <math.h>

#define N_NODES 100000
#define NPAD 100032         // 1563 * 64, padded row count for 64-row GEMM tiles
#define N_EDGES 1600000
#define EPS 1e-5f
#define NC 256              // edge chunks
#define CHUNK 6250          // N_EDGES / NC
#define NR 98               // ceil(100000/1024) dst ranges
#define RSZ 1024            // nodes per range
#define NRC (NR * NC)       // 25088
#define EIXL_CAP 1792       // staged edge-index capacity (mean 1024 + 24 sigma)

typedef __bf16 bf16x8 __attribute__((ext_vector_type(8)));
typedef float f32x4 __attribute__((ext_vector_type(4)));
typedef float f32x2 __attribute__((ext_vector_type(2)));

__device__ inline unsigned short f2bf(float f) {    // RNE, finite inputs
    unsigned u = __float_as_uint(f);
    unsigned r = u + 0x7fffu + ((u >> 16) & 1u);
    return (unsigned short)(r >> 16);
}
__device__ inline float bflo(unsigned u) { return __uint_as_float(u << 16); }
__device__ inline float bfhi(unsigned u) { return __uint_as_float(u & 0xffff0000u); }
__device__ inline unsigned pack2(float lo, float hi) {
    return (unsigned)f2bf(lo) | ((unsigned)f2bf(hi) << 16);
}
__device__ inline unsigned char f2fp8(float f) {    // e4m3 via HW cvt
    return (unsigned char)(__builtin_amdgcn_cvt_pk_fp8_f32(f, f, 0, false) & 0xff);
}

// ============ fused prep: x->bf16+fp8 cast (blocks 0..12499) + dst-range
// histogram (blocks 12500..12755) ============
__global__ __launch_bounds__(256) void k_prep(const float* __restrict__ x,
                                              unsigned short* __restrict__ xb,
                                              unsigned* __restrict__ xq8,
                                              const int* __restrict__ dst,
                                              int* __restrict__ cntG) {
    __shared__ int hist[NR];
    int t = threadIdx.x;
    if (blockIdx.x < 12500) {
        int idx = blockIdx.x * 256 + t;     // < N_NODES*32 float4
        float4 v = ((const float4*)x)[idx];
        ushort4 o;
        o.x = f2bf(v.x); o.y = f2bf(v.y); o.z = f2bf(v.z); o.w = f2bf(v.w);
        ((ushort4*)xb)[idx] = o;
        int q = __builtin_amdgcn_cvt_pk_fp8_f32(v.x, v.y, 0, false);
        q = __builtin_amdgcn_cvt_pk_fp8_f32(v.z, v.w, q, true);
        xq8[idx] = (unsigned)q;
    } else {
        int c = blockIdx.x - 12500;
        for (int i = t; i < NR; i += 256) hist[i] = 0;
        __syncthreads();
        int base = c * CHUNK;
        for (int i = base + t; i < base + CHUNK; i += 256)
            atomicAdd(&hist[dst[i] >> 10], 1);
        __syncthreads();
        for (int i = t; i < NR; i += 256) cntG[i * NC + c] = hist[i];
    }
}

// ============ fused: exclusive scan of cntG (block 0) + weight prep
// (blocks 1..320) ============
__global__ __launch_bounds__(256) void k_scanA_prepw(
        int* __restrict__ cntG,
        const float* __restrict__ Wr0, const float* __restrict__ Wn0,
        const float* __restrict__ Wr1, const float* __restrict__ Wn1,
        const float* __restrict__ Wr2, const float* __restrict__ Wn2,
        unsigned short* __restrict__ WT0, unsigned short* __restrict__ WT1,
        unsigned short* __restrict__ WT2) {
    int t = threadIdx.x;
    if (blockIdx.x == 0) {
        __shared__ int ts[256];
        const int PER = NRC / 256;          // 98
        int s = 0;
        for (int i = 0; i < PER; ++i) s += cntG[t * PER + i];
        ts[t] = s;
        __syncthreads();
        #pragma unroll
        for (int off = 1; off < 256; off <<= 1) {
            int y = 0;
            if (t >= off) y = ts[t - off];
            __syncthreads();
            if (t >= off) ts[t] += y;
            __syncthreads();
        }
        int run = ts[t] - s;                // exclusive
        for (int i = 0; i < PER; ++i) {
            int v = cntG[t * PER + i];
            cntG[t * PER + i] = run;
            run += v;
        }
    } else {
        int b = blockIdx.x - 1;
        if (b < 256) {
            const float* Wr = (b < 128) ? Wr0 : Wr1;
            const float* Wn = (b < 128) ? Wn0 : Wn1;
            unsigned short* WT = (b < 128) ? WT0 : WT1;
            int idx = (b & 127) * 256 + t;
            int n = idx >> 8;
            int kc = idx & 255;
            float v = (kc < 128) ? Wr[kc * 128 + n] : Wn[(kc - 128) * 128 + n];
            WT[idx] = f2bf(v);
        } else {
            int idx = (b - 256) * 256 + t;  // < 128*128
            int n = idx >> 7;
            int k = idx & 127;
            float v = (n < 64) ? Wr2[k * 64 + n] : Wn2[k * 64 + (n - 64)];
            WT2[n * 128 + k] = f2bf(v);
        }
    }
}

// ============ bin edges by dst-range; packed (src<<10 | dstlocal) ============
__global__ __launch_bounds__(1024) void k_bin(const int* __restrict__ src,
                                              const int* __restrict__ dst,
                                              const int* __restrict__ baseG,
                                              unsigned* __restrict__ bpack) {
    __shared__ int cur[NR];
    int t = threadIdx.x, c = blockIdx.x;
    for (int i = t; i < NR; i += 1024) cur[i] = baseG[i * NC + c];
    __syncthreads();
    int base = c * CHUNK;
    for (int i = base + t; i < base + CHUNK; i += 1024) {
        int d = dst[i];
        unsigned s = (unsigned)src[i];
        int p = atomicAdd(&cur[d >> 10], 1);
        bpack[p] = (s << 10) | (unsigned)(d & 1023);
    }
}

// ============ fused per-range: histogram -> deg/invdeg/rowptr -> place =====
__global__ __launch_bounds__(1024) void k_nodeplace(
        const unsigned* __restrict__ bpack, const int* __restrict__ baseG,
        int* __restrict__ deg, float* __restrict__ invdeg,
        int* __restrict__ rowptr, int* __restrict__ eidx) {
    __shared__ int hist[RSZ];
    __shared__ int cur[RSZ];
    __shared__ int wbase[16];
    int r = blockIdx.x, t = threadIdx.x;
    hist[t] = 0;
    __syncthreads();
    int s0 = baseG[r * NC];
    int s1 = (r == NR - 1) ? N_EDGES : baseG[(r + 1) * NC];
    int nbase = r << 10;
    for (int i = s0 + t; i < s1; i += 1024)
        atomicAdd(&hist[bpack[i] & 1023u], 1);
    __syncthreads();
    int lane = t & 63, wv = t >> 6;
    int d = hist[t];
    int s = d;                              // wave-inclusive scan
    #pragma unroll
    for (int m = 1; m < 64; m <<= 1) {
        int y = __shfl_up(s, m);
        if (lane >= m) s += y;
    }
    if (lane == 63) wbase[wv] = s;
    __syncthreads();
    if (t < 16) {                           // scan the 16 wave totals
        int v = wbase[t];
        int sv = v;
        #pragma unroll
        for (int m = 1; m < 16; m <<= 1) {
            int y = __shfl_up(sv, m);
            if (t >= m) sv += y;
        }
        wbase[t] = sv - v;                  // exclusive wave base
    }
    __syncthreads();
    int p = s0 + wbase[wv] + s - d;         // exclusive prefix for counter t
    cur[t] = p;
    int n = nbase + t;
    if (n < N_NODES) {
        rowptr[n] = p;
        deg[n] = d;
        invdeg[n] = 1.0f / fmaxf((float)d, 1.0f);
    }
    __syncthreads();
    for (int i = s0 + t; i < s1; i += 1024) {
        unsigned bp = bpack[i];
        int pp = atomicAdd(&cur[bp & 1023u], 1);
        eidx[pp] = (int)(bp >> 10);
    }
}

// ------ MFMA dual-GEMM + bias + LayerNorm + ReLU (K=256 -> 128), 64 rows ---
// r6 empirical optimum (54.7us/dispatch): fused gather, selfA in regs,
// bt K=32 LDS staging, LDS = al 17.4K + bt 10.2K + p 1K + eixl 7K = 35.8KB
// -> 4 blocks/CU, occupancy ~61%. Bracketing experiments: B-from-global
// (r7/r8) and epilogue gemm2 fusion (r8) both regress — keep bt in LDS and
// gemm2 separate.
__global__ __launch_bounds__(512, 8) void k_gemm_ln(
        const unsigned short* __restrict__ hb,
        const uint4* __restrict__ hq4,
        const int* __restrict__ eidx, const int* __restrict__ rowptr,
        const int* __restrict__ deg, const float* __restrict__ invdeg,
        const unsigned short* __restrict__ WT,
        const float* __restrict__ b, const float* __restrict__ g,
        const float* __restrict__ be, unsigned short* __restrict__ outb,
        unsigned char* __restrict__ outq8) {
    __shared__ unsigned short al[64][136];
    __shared__ unsigned short bt[128][40];
    __shared__ float p1[2][64], p2[2][64];
    __shared__ int eixl[EIXL_CAP];

    const int tid = threadIdx.x;
    const int lane = tid & 63;
    const int w = tid >> 6;
    const int quad = lane >> 4;
    const int l15 = lane & 15;
    const int rt = w >> 1;
    const int ch = w & 1;
    const int row0 = blockIdx.x * 64;

    // self A-fragments (K 0..127) straight to registers; issued first so the
    // loads ride under the gather latency
    bf16x8 selfA[4];
    {
        const unsigned short* base = hb + (size_t)(row0 + rt * 16 + l15) * 128 + quad * 8;
        #pragma unroll
        for (int kt = 0; kt < 4; ++kt)
            selfA[kt] = *(const bf16x8*)(base + kt * 32);
    }

    // stage this block's contiguous edge-index segment
    int e0 = rowptr[row0];
    int e1 = (row0 + 64 < N_NODES) ? rowptr[row0 + 64] : N_EDGES;
    int nE = e1 - e0;
    int staged = nE < EIXL_CAP ? nE : EIXL_CAP;
    for (int i = tid; i < staged; i += 512) eixl[i] = eidx[e0 + i];
    __syncthreads();

    // fused gather: node = row0 + tid/8, lane l = tid&7 owns 16B of the row
    {
        int r = tid >> 3;               // 0..63
        int l = tid & 7;
        int node = row0 + r;
        uint4 o0 = {0, 0, 0, 0}, o1 = {0, 0, 0, 0};
        if (node < N_NODES) {
            int start = rowptr[node];
            int cnt = deg[node];
            int rel = start - e0;
            f32x2 a[8];
            #pragma unroll
            for (int i = 0; i < 8; ++i) a[i] = (f32x2)0.0f;
            auto accum = [&](uint4 u) {
                a[0] += __builtin_amdgcn_cvt_pk_f32_fp8((int)u.x, false);
                a[1] += __builtin_amdgcn_cvt_pk_f32_fp8((int)u.x, true);
                a[2] += __builtin_amdgcn_cvt_pk_f32_fp8((int)u.y, false);
                a[3] += __builtin_amdgcn_cvt_pk_f32_fp8((int)u.y, true);
                a[4] += __builtin_amdgcn_cvt_pk_f32_fp8((int)u.z, false);
                a[5] += __builtin_amdgcn_cvt_pk_f32_fp8((int)u.z, true);
                a[6] += __builtin_amdgcn_cvt_pk_f32_fp8((int)u.w, false);
                a[7] += __builtin_amdgcn_cvt_pk_f32_fp8((int)u.w, true);
            };
            if (rel + cnt <= staged) {      // whole node staged (normal case)
                int j = 0;
                for (; j + 4 <= cnt; j += 4) {
                    int i0 = eixl[rel + j + 0], i1 = eixl[rel + j + 1];
                    int i2 = eixl[rel + j + 2], i3 = eixl[rel + j + 3];
                    uint4 u0 = hq4[(unsigned)(i0 * 8 + l)];
                    uint4 u1 = hq4[(unsigned)(i1 * 8 + l)];
                    uint4 u2 = hq4[(unsigned)(i2 * 8 + l)];
                    uint4 u3 = hq4[(unsigned)(i3 * 8 + l)];
                    accum(u0); accum(u1); accum(u2); accum(u3);
                }
                for (; j < cnt; ++j) {
                    uint4 u = hq4[(unsigned)(eixl[rel + j] * 8 + l)];
                    accum(u);
                }
            } else {                        // overflow fallback (astronomically rare)
                int j = 0;
                for (; j + 4 <= cnt; j += 4) {
                    int s0 = eidx[start + j];
                    int s1 = eidx[start + j + 1];
                    int s2 = eidx[start + j + 2];
                    int s3 = eidx[start + j + 3];
                    uint4 u0 = hq4[(unsigned)(s0 * 8 + l)];
                    uint4 u1 = hq4[(unsigned)(s1 * 8 + l)];
                    uint4 u2 = hq4[(unsigned)(s2 * 8 + l)];
                    uint4 u3 = hq4[(unsigned)(s3 * 8 + l)];
                    accum(u0); accum(u1); accum(u2); accum(u3);
                }
                for (; j < cnt; ++j) {
                    uint4 u = hq4[(unsigned)(eidx[start + j] * 8 + l)];
                    accum(u);
                }
            }
            float id = invdeg[node];
            o0.x = pack2(a[0].x * id, a[0].y * id);
            o0.y = pack2(a[1].x * id, a[1].y * id);
            o0.z = pack2(a[2].x * id, a[2].y * id);
            o0.w = pack2(a[3].x * id, a[3].y * id);
            o1.x = pack2(a[4].x * id, a[4].y * id);
            o1.y = pack2(a[5].x * id, a[5].y * id);
            o1.z = pack2(a[6].x * id, a[6].y * id);
            o1.w = pack2(a[7].x * id, a[7].y * id);
        }
        *(uint4*)&al[r][l * 16] = o0;
        *(uint4*)&al[r][l * 16 + 8] = o1;
    }

    f32x4 acc[4];
    #pragma unroll
    for (int t = 0; t < 4; ++t)
        #pragma unroll
        for (int r = 0; r < 4; ++r) acc[t][r] = 0.0f;

    // K loop: 8 steps of K=32; bt stages 128 N-rows x 32 k each step.
    // A-frag: kt<4 -> register selfA; kt>=4 -> ds_read from al.
    #pragma unroll
    for (int kt = 0; kt < 8; ++kt) {
        __syncthreads();
        {
            int n = tid >> 2;           // 0..127
            int c = tid & 3;            // 4 x float4 = 32 k-cols
            *(float4*)&bt[n][c * 8] = ((const float4*)WT)[n * 32 + kt * 4 + c];
        }
        __syncthreads();
        bf16x8 a = (kt < 4)
            ? selfA[kt]
            : *(const bf16x8*)&al[rt * 16 + l15][(kt - 4) * 32 + quad * 8];
        #pragma unroll
        for (int t = 0; t < 4; ++t) {
            bf16x8 bb = *(const bf16x8*)&bt[ch * 64 + t * 16 + l15][quad * 8];
            acc[t] = __builtin_amdgcn_mfma_f32_16x16x32_bf16(a, bb, acc[t], 0, 0, 0);
        }
    }

    float bcol[4], gc[4], bec[4];
    #pragma unroll
    for (int t = 0; t < 4; ++t) {
        int col = ch * 64 + t * 16 + l15;
        bcol[t] = b[col]; gc[t] = g[col]; bec[t] = be[col];
    }
    float v[4][4];
    float s1[4], s2[4];
    #pragma unroll
    for (int r = 0; r < 4; ++r) { s1[r] = 0.0f; s2[r] = 0.0f; }
    #pragma unroll
    for (int t = 0; t < 4; ++t)
        #pragma unroll
        for (int r = 0; r < 4; ++r) {
            float x = acc[t][r] + bcol[t];
            v[t][r] = x;
            s1[r] += x;
            s2[r] += x * x;
        }
    #pragma unroll
    for (int m = 1; m <= 8; m <<= 1)
        #pragma unroll
        for (int r = 0; r < 4; ++r) {
            s1[r] += __shfl_xor(s1[r], m);
            s2[r] += __shfl_xor(s2[r], m);
        }
    if (l15 == 0) {
        #pragma unroll
        for (int r = 0; r < 4; ++r) {
            int rl = rt * 16 + quad * 4 + r;
            p1[ch][rl] = s1[r];
            p2[ch][rl] = s2[r];
        }
    }
    __syncthreads();
    #pragma unroll
    for (int r = 0; r < 4; ++r) {
        int rl = rt * 16 + quad * 4 + r;
        float S1 = p1[0][rl] + p1[1][rl];
        float S2 = p2[0][rl] + p2[1][rl];
        float mean = S1 * (1.0f / 128.0f);
        float var = S2 * (1.0f / 128.0f) - mean * mean;
        float rstd = rsqrtf(var + EPS);
        #pragma unroll
        for (int t = 0; t < 4; ++t) {
            int col = ch * 64 + t * 16 + l15;
            float o = fmaxf((v[t][r] - mean) * rstd * gc[t] + bec[t], 0.0f);
            outb[(size_t)(row0 + rl) * 128 + col] = f2bf(o);
            if (outq8) outq8[(size_t)(row0 + rl) * 128 + col] = f2fp8(o);
        }
    }
}

// ------ layer 2 GEMM: z(+b2) -> bf16, y -> fp8 shadow, 64 rows -------------
__global__ __launch_bounds__(512) void k_gemm2(
        const unsigned short* __restrict__ hb, const unsigned short* __restrict__ WT,
        const float* __restrict__ b2, unsigned short* __restrict__ zb16,
        unsigned char* __restrict__ yq8) {
    __shared__ unsigned short hl[64][136];
    __shared__ unsigned short bt[128][136];

    const int tid = threadIdx.x;
    const int lane = tid & 63;
    const int w = tid >> 6;
    const int quad = lane >> 4;
    const int l15 = lane & 15;
    const int rt = w >> 1;
    const int ch = w & 1;
    const int row0 = blockIdx.x * 64;

    #pragma unroll
    for (int t = 0; t < 2; ++t) {
        int idx = tid + t * 512;
        int r = idx >> 4;
        int c8 = idx & 15;
        *(float4*)&hl[r][c8 * 8] = ((const float4*)hb)[(size_t)(row0 + r) * 16 + c8];
    }
    #pragma unroll
    for (int t = 0; t < 4; ++t) {
        int idx = tid + t * 512;
        int n = idx >> 4;
        int c8 = idx & 15;
        *(float4*)&bt[n][c8 * 8] = ((const float4*)WT)[n * 16 + c8];
    }
    __syncthreads();

    f32x4 acc[4];
    #pragma unroll
    for (int t = 0; t < 4; ++t)
        #pragma unroll
        for (int r = 0; r < 4; ++r) acc[t][r] = 0.0f;

    #pragma unroll
    for (int ks = 0; ks < 4; ++ks) {
        bf16x8 a = *(const bf16x8*)&hl[rt * 16 + l15][ks * 32 + quad * 8];
        #pragma unroll
        for (int t = 0; t < 4; ++t) {
            bf16x8 bb = *(const bf16x8*)&bt[ch * 64 + t * 16 + l15][ks * 32 + quad * 8];
            acc[t] = __builtin_amdgcn_mfma_f32_16x16x32_bf16(a, bb, acc[t], 0, 0, 0);
        }
    }

    if (ch == 0) {      // z half: cols 0..63, + bias, bf16
        #pragma unroll
        for (int t = 0; t < 4; ++t) {
            int col = t * 16 + l15;
            float bc = b2[col];
            #pragma unroll
            for (int r = 0; r < 4; ++r) {
                int rl = rt * 16 + quad * 4 + r;
                zb16[(size_t)(row0 + rl) * 64 + col] = f2bf(acc[t][r] + bc);
            }
        }
    } else {            // y half: cols 0..63 of y, fp8
        #pragma unroll
        for (int t = 0; t < 4; ++t) {
            int col = t * 16 + l15;
            #pragma unroll
            for (int r = 0; r < 4; ++r) {
                int rl = rt * 16 + quad * 4 + r;
                yq8[(size_t)(row0 + rl) * 64 + col] = f2fp8(acc[t][r]);
            }
        }
    }
}

// ------- final: gather-mean y (fp8, 64-dim) + z + log_softmax, fp32 out ----
__global__ __launch_bounds__(256) void k_l2g(const uint4* __restrict__ yq4,
                                             const unsigned short* __restrict__ zb16,
                                             const int* __restrict__ eidx,
                                             const int* __restrict__ rowptr,
                                             const int* __restrict__ deg,
                                             const float* __restrict__ invdeg,
                                             float* __restrict__ out) {
    __shared__ int eixl[EIXL_CAP];
    int node0 = blockIdx.x * 64;
    int e0 = rowptr[node0];
    int e1 = (node0 + 64 < N_NODES) ? rowptr[node0 + 64] : N_EDGES;
    int nE = e1 - e0;
    int staged = nE < EIXL_CAP ? nE : EIXL_CAP;
    for (int i = threadIdx.x; i < staged; i += 256) eixl[i] = eidx[e0 + i];
    __syncthreads();

    int node = node0 + (threadIdx.x >> 2);
    if (node >= N_NODES) return;   // after the only barrier — safe
    int l = threadIdx.x & 3;       // 16B chunk of the 64B fp8 y row
    int start = rowptr[node];
    int cnt = deg[node];
    int rel = start - e0;
    f32x2 a[8];
    #pragma unroll
    for (int i = 0; i < 8; ++i) a[i] = (f32x2)0.0f;

    auto accum = [&](uint4 u) {
        a[0] += __builtin_amdgcn_cvt_pk_f32_fp8((int)u.x, false);
        a[1] += __builtin_amdgcn_cvt_pk_f32_fp8((int)u.x, true);
        a[2] += __builtin_amdgcn_cvt_pk_f32_fp8((int)u.y, false);
        a[3] += __builtin_amdgcn_cvt_pk_f32_fp8((int)u.y, true);
        a[4] += __builtin_amdgcn_cvt_pk_f32_fp8((int)u.z, false);
        a[5] += __builtin_amdgcn_cvt_pk_f32_fp8((int)u.z, true);
        a[6] += __builtin_amdgcn_cvt_pk_f32_fp8((int)u.w, false);
        a[7] += __builtin_amdgcn_cvt_pk_f32_fp8((int)u.w, true);
    };

    if (rel + cnt <= staged) {
        int nb = cnt >> 3;
        for (int bq = 0; bq < nb; ++bq) {
            int jb = rel + bq * 8;
            int i0 = eixl[jb + 0], i1 = eixl[jb + 1];
            int i2 = eixl[jb + 2], i3 = eixl[jb + 3];
            int i4 = eixl[jb + 4], i5 = eixl[jb + 5];
            int i6 = eixl[jb + 6], i7 = eixl[jb + 7];
            uint4 u0 = yq4[(unsigned)(i0 * 4 + l)];
            uint4 u1 = yq4[(unsigned)(i1 * 4 + l)];
            uint4 u2 = yq4[(unsigned)(i2 * 4 + l)];
            uint4 u3 = yq4[(unsigned)(i3 * 4 + l)];
            uint4 u4 = yq4[(unsigned)(i4 * 4 + l)];
            uint4 u5 = yq4[(unsigned)(i5 * 4 + l)];
            uint4 u6 = yq4[(unsigned)(i6 * 4 + l)];
            uint4 u7 = yq4[(unsigned)(i7 * 4 + l)];
            accum(u0); accum(u1); accum(u2); accum(u3);
            accum(u4); accum(u5); accum(u6); accum(u7);
        }
        int j = nb << 3;
        int rem = cnt - j;
        #pragma unroll
        for (int k = 0; k < 8; ++k) {
            if (k < rem) {
                uint4 u = yq4[(unsigned)(eixl[rel + j + k] * 4 + l)];
                accum(u);
            }
        }
    } else {                        // overflow fallback (astronomically rare)
        int j = 0;
        for (; j + 4 <= cnt; j += 4) {
            int s0 = eidx[start + j];
            int s1 = eidx[start + j + 1];
            int s2 = eidx[start + j + 2];
            int s3 = eidx[start + j + 3];
            uint4 u0 = yq4[(unsigned)(s0 * 4 + l)];
            uint4 u1 = yq4[(unsigned)(s1 * 4 + l)];
            uint4 u2 = yq4[(unsigned)(s2 * 4 + l)];
            uint4 u3 = yq4[(unsigned)(s3 * 4 + l)];
            accum(u0); accum(u1); accum(u2); accum(u3);
        }
        for (; j < cnt; ++j) {
            uint4 u = yq4[(unsigned)(eidx[start + j] * 4 + l)];
            accum(u);
        }
    }

    // v = z + mean(y) for cols 16l..16l+15
    float id = invdeg[node];
    uint4 z0 = ((const uint4*)zb16)[(size_t)node * 8 + l * 2];
    uint4 z1 = ((const uint4*)zb16)[(size_t)node * 8 + l * 2 + 1];
    float v[16];
    v[0]  = bflo(z0.x) + a[0].x * id; v[1]  = bfhi(z0.x) + a[0].y * id;
    v[2]  = bflo(z0.y) + a[1].x * id; v[3]  = bfhi(z0.y) + a[1].y * id;
    v[4]  = bflo(z0.z) + a[2].x * id; v[5]  = bfhi(z0.z) + a[2].y * id;
    v[6]  = bflo(z0.w) + a[3].x * id; v[7]  = bfhi(z0.w) + a[3].y * id;
    v[8]  = bflo(z1.x) + a[4].x * id; v[9]  = bfhi(z1.x) + a[4].y * id;
    v[10] = bflo(z1.y) + a[5].x * id; v[11] = bfhi(z1.y) + a[5].y * id;
    v[12] = bflo(z1.z) + a[6].x * id; v[13] = bfhi(z1.z) + a[6].y * id;
    v[14] = bflo(z1.w) + a[7].x * id; v[15] = bfhi(z1.w) + a[7].y * id;

    float m = v[0];
    #pragma unroll
    for (int i = 1; i < 16; ++i) m = fmaxf(m, v[i]);
    m = fmaxf(m, __shfl_xor(m, 1));
    m = fmaxf(m, __shfl_xor(m, 2));
    float s = 0.0f;
    #pragma unroll
    for (int i = 0; i < 16; ++i) s += __expf(v[i] - m);
    s += __shfl_xor(s, 1);
    s += __shfl_xor(s, 2);
    float L = m + logf(s);
    #pragma unroll
    for (int k = 0; k < 4; ++k) {
        float4 o;
        o.x = v[4 * k] - L; o.y = v[4 * k + 1] - L;
        o.z = v[4 * k + 2] - L; o.w = v[4 * k + 3] - L;
        ((float4*)out)[(size_t)node * 16 + l * 4 + k] = o;
    }
}

extern "C" void kernel_launch(void* const* d_in, const int* in_sizes, int n_in,
                              void* d_out, int out_size, void* d_ws, size_t ws_size,
                              hipStream_t stream) {
    const float* x   = (const float*)d_in[0];
    const int* esrc  = (const int*)d_in[1];
    const int* edst  = (const int*)d_in[2];
    const float* Wr0 = (const float*)d_in[3];
    const float* Wn0 = (const float*)d_in[4];
    const float* b0  = (const float*)d_in[5];
    const float* g0  = (const float*)d_in[6];
    const float* be0 = (const float*)d_in[7];
    const float* Wr1 = (const float*)d_in[8];
    const float* Wn1 = (const float*)d_in[9];
    const float* b1  = (const float*)d_in[10];
    const float* g1  = (const float*)d_in[11];
    const float* be1 = (const float*)d_in[12];
    const float* Wr2 = (const float*)d_in[13];
    const float* Wn2 = (const float*)d_in[14];
    const float* b2  = (const float*)d_in[15];
    float* out = (float*)d_out;

    char* p = (char*)d_ws;
    auto alloc = [&](size_t bytes) {
        void* r = (void*)p;
        p += (bytes + 255) & ~(size_t)255;
        return r;
    };
    int*   deg    = (int*)  alloc(N_NODES * 4);
    float* invdeg = (float*)alloc(N_NODES * 4);
    int*   rowptr = (int*)  alloc(N_NODES * 4);
    int*   cntG   = (int*)  alloc(NRC * 4);
    unsigned* bpack = (unsigned*)alloc((size_t)N_EDGES * 4);
    int*   eidx   = (int*)  alloc((size_t)N_EDGES * 4);
    unsigned short* xb   = (unsigned short*)alloc((size_t)NPAD * 128 * 2); // also h2
    unsigned short* h1   = (unsigned short*)alloc((size_t)NPAD * 128 * 2);
    unsigned*       xq8  = (unsigned*)      alloc((size_t)N_NODES * 128);
    unsigned char*  h1q8 = (unsigned char*) alloc((size_t)NPAD * 128);
    unsigned short* zb16 = (unsigned short*)alloc((size_t)NPAD * 64 * 2);
    unsigned char*  yq8  = (unsigned char*) alloc((size_t)NPAD * 64);
    unsigned short* WT0  = (unsigned short*)alloc(128 * 256 * 2);
    unsigned short* WT1  = (unsigned short*)alloc(128 * 256 * 2);
    unsigned short* WT2  = (unsigned short*)alloc(128 * 128 * 2);

    // prep (cast bf16+fp8 + dst-range count); scan + weight transpose
    k_prep<<<12500 + NC, 256, 0, stream>>>(x, xb, xq8, edst, cntG);
    k_scanA_prepw<<<321, 256, 0, stream>>>(cntG, Wr0, Wn0, Wr1, Wn1, Wr2, Wn2,
                                           WT0, WT1, WT2);
    k_bin<<<NC, 1024, 0, stream>>>(esrc, edst, cntG, bpack);
    k_nodeplace<<<NR, 1024, 0, stream>>>(bpack, cntG, deg, invdeg, rowptr, eidx);

    // layer 0 (gather fused into the GEMM)
    k_gemm_ln<<<NPAD / 64, 512, 0, stream>>>(xb, (const uint4*)xq8, eidx, rowptr,
                                             deg, invdeg, WT0, b0, g0, be0, h1, h1q8);

    // layer 1 (h2 goes back into xb's buffer; no fp8 copy needed)
    k_gemm_ln<<<NPAD / 64, 512, 0, stream>>>(h1, (const uint4*)h1q8, eidx, rowptr,
                                             deg, invdeg, WT1, b1, g1, be1, xb,
                                             (unsigned char*)nullptr);

    // layer 2: z (bf16) + y (fp8), then gather y + log_softmax
    k_gemm2<<<NPAD / 64, 512, 0, stream>>>(xb, WT2, b2, zb16, yq8);
    k_l2g<<<(N_NODES + 63) / 64, 256, 0, stream>>>((const uint4*)yq8, zb16, eidx, rowptr, deg, invdeg, out);
}